// Round 18
// baseline (697.659 us; speedup 1.0000x reference)
//
#include <hip/hip_runtime.h>
#include <hip/hip_bf16.h>

#define DIM   4096
#define NH    32
#define HD    128
#define BATCH 2
#define SEQ   1024
#define MROWS (BATCH*SEQ)   // 2048
#define LDQ   12288         // fused qkv row stride

typedef __attribute__((ext_vector_type(8))) short bf16x8;
typedef __attribute__((ext_vector_type(4))) short s16x4;
typedef __attribute__((ext_vector_type(4))) float f32x4;

__device__ inline void gload_lds16(const void* g, void* l) {
  __builtin_amdgcn_global_load_lds(
      (const __attribute__((address_space(1))) void*)g,
      (__attribute__((address_space(3))) void*)l, 16, 0, 0);
}

__device__ inline float bf2f(short b) {
  unsigned u = ((unsigned)(unsigned short)b) << 16;
  return __uint_as_float(u);
}
__device__ inline unsigned short f2bfu(float f) {
  __hip_bfloat16 h = __float2bfloat16(f);
  return *reinterpret_cast<unsigned short*>(&h);
}

// ---------------- merged prep: bias concat + rope table + fp32->bf16 cvt -----
__global__ void prep_kernel(const float* __restrict__ x, const float* __restrict__ wq,
                            const float* __restrict__ wk, const float* __restrict__ wv,
                            const float* __restrict__ wo,
                            const float* __restrict__ bq, const float* __restrict__ bk,
                            const float* __restrict__ bv,
                            unsigned short* __restrict__ xb,
                            unsigned short* __restrict__ wqkvb,
                            unsigned short* __restrict__ wob,
                            float* __restrict__ biasqkv,
                            float* __restrict__ cosT, float* __restrict__ sinT) {
  const long NB = 12288;
  const long NR = 65536;            // SEQ * 64
  const long NX = 2l << 20;         // x float4 count
  const long NW = 4l << 20;         // per-weight float4 count
  const long total = NB + NR + NX + 4 * NW;
  long i = blockIdx.x * (long)blockDim.x + threadIdx.x;
  long stride = (long)gridDim.x * blockDim.x;
  for (; i < total; i += stride) {
    if (i < NB) {
      int j = (int)i;
      float v = (j < 4096) ? bq[j] : (j < 8192 ? bk[j - 4096] : bv[j - 8192]);
      biasqkv[j] = v;
    } else if (i < NB + NR) {
      int j = (int)(i - NB);
      int s = j >> 6, p = j & 63;
      float inv = powf(10000.0f, -((float)(2 * p)) / 128.0f);
      float a = (float)s * inv;
      cosT[j] = cosf(a);
      sinT[j] = sinf(a);
    } else {
      long j = i - NB - NR;
      const float* src; unsigned short* dst; long off;
      if (j < NX) { src = x; dst = xb; off = j; }
      else {
        long q = j - NX;
        int wsel = (int)(q >> 22);
        off = q & (NW - 1);
        if (wsel == 0)      { src = wq; dst = wqkvb; }
        else if (wsel == 1) { src = wk; dst = wqkvb + (size_t)DIM * DIM; }
        else if (wsel == 2) { src = wv; dst = wqkvb + 2 * (size_t)DIM * DIM; }
        else                { src = wo; dst = wob; }
      }
      float4 v = ((const float4*)src)[off];
      ushort4 o;
      o.x = f2bfu(v.x); o.y = f2bfu(v.y); o.z = f2bfu(v.z); o.w = f2bfu(v.w);
      ((ushort4*)dst)[off] = o;
    }
  }
}

// ---------------- m97+ GEMM: 128x128 tile, 3-slot rolling, depth 2 -----------
// R13/R15/R17-VERIFIED OPTIMUM: QKV ~280 us / 740 TF, FETCH 200 MB,
// conflicts 0, occupancy ~33% (3 blocks/CU). Do not change (all axes measured).
template <typename OutT, bool ROPE>
__global__ __launch_bounds__(256, 2) void gemm_m97p_kernel(
    const unsigned short* __restrict__ A, const unsigned short* __restrict__ Bw,
    const float* __restrict__ bias, OutT* __restrict__ C,
    int M, int N, int Kstr,
    const float* __restrict__ cosT, const float* __restrict__ sinT) {
  __shared__ unsigned short As[3][128 * 32];   // 24 KB
  __shared__ unsigned short Bs[3][128 * 32];   // 24 KB
  const int t = threadIdx.x;
  const int lane = t & 63;
  const int w = t >> 6;                 // 4 waves
  const int wm = w >> 1, wn = w & 1;    // 2x2
  const int np = lane & 15, hq = lane >> 4;
  const int kc = ((hq ^ ((np >> 1) & 3)) << 3);

  // B-optimal XCD mapping: XCD = bid%8 owns bx in [k*sw, (k+1)*sw), by-major.
  int bid = blockIdx.y * gridDim.x + blockIdx.x;
  int k = bid & 7;
  int local = bid >> 3;
  int sw = gridDim.x >> 3;
  int bx = k * sw + local / gridDim.y;
  int by = local % gridDim.y;
  const int m0 = by * 128, n0 = bx * 128;
  const int H = Kstr >> 5;

  auto stage = [&](int slot, int kcol0) {
#pragma unroll
    for (int j = 0; j < 2; ++j) {
      int ci = j * 256 + t;                       // [0,512)
      int r = ci >> 2, p = ci & 3, g = p ^ ((r >> 1) & 3);
      gload_lds16(A + (size_t)(m0 + r) * Kstr + kcol0 + g * 8, &As[slot][ci * 8]);
    }
#pragma unroll
    for (int j = 0; j < 2; ++j) {
      int ci = j * 256 + t;
      int r = ci >> 2, p = ci & 3, g = p ^ ((r >> 1) & 3);
      gload_lds16(Bw + (size_t)(n0 + r) * Kstr + kcol0 + g * 8, &Bs[slot][ci * 8]);
    }
  };

  stage(0, 0); stage(1, 32);
  asm volatile("s_waitcnt vmcnt(4)" ::: "memory");
  __builtin_amdgcn_s_barrier();

  f32x4 acc[4][4] = {};

  int sl = 0;
#pragma unroll 1
  for (int u = 0; u < H; ++u) {
    const unsigned short* Asl = As[sl];
    const unsigned short* Bsl = Bs[sl];
    bf16x8 af[4], bfr[4];
#pragma unroll
    for (int i = 0; i < 4; ++i)
      af[i] = *(const bf16x8*)&Asl[(wm * 64 + i * 16 + np) * 32 + kc];
#pragma unroll
    for (int j = 0; j < 4; ++j)
      bfr[j] = *(const bf16x8*)&Bsl[(wn * 64 + j * 16 + np) * 32 + kc];

    if (u + 2 < H) {
      int ssl = sl + 2; if (ssl >= 3) ssl -= 3;
      stage(ssl, (u + 2) << 5);
    }

    __builtin_amdgcn_s_setprio(1);
#pragma unroll
    for (int i = 0; i < 4; ++i)
#pragma unroll
      for (int j = 0; j < 4; ++j)
        acc[i][j] = __builtin_amdgcn_mfma_f32_16x16x32_bf16(af[i], bfr[j], acc[i][j], 0, 0, 0);
    __builtin_amdgcn_s_setprio(0);

    if (u + 1 < H) {
      if (u + 2 < H) asm volatile("s_waitcnt vmcnt(4)" ::: "memory");
      else           asm volatile("s_waitcnt vmcnt(0)" ::: "memory");
      __builtin_amdgcn_s_barrier();
    }
    sl = (sl == 2) ? 0 : sl + 1;
  }

  const int orow0 = m0 + wm * 64;
  const int ocol0 = n0 + wn * 64 + np;
#pragma unroll
  for (int j = 0; j < 4; ++j) {
    const int col = ocol0 + j * 16;
    float bj = bias[col];
    const int p0 = (col & 127) >> 1;
    const bool even = (lane & 1) == 0;
    const bool do_rope = ROPE && (col < 8192);
#pragma unroll
    for (int i = 0; i < 4; ++i) {
#pragma unroll
      for (int r = 0; r < 4; ++r) {
        int orow = orow0 + i * 16 + hq * 4 + r;
        float v = acc[i][j][r] + bj;
        float pv = __shfl_xor(v, 1);
        if (do_rope) {
          int srow = orow & (SEQ - 1);
          float c = cosT[srow * 64 + p0];
          float s = sinT[srow * 64 + p0];
          v = even ? (v * c - pv * s) : (pv * s + v * c);
        }
        size_t off = (size_t)orow * N + col;
        if constexpr (sizeof(OutT) == 2)
          ((unsigned short*)C)[off] = f2bfu(v);
        else
          ((float*)C)[off] = v;
      }
    }
  }
}

// ---------------- Flash attention v3 (causal), QBLK=64, 128 thr = 2 waves ----
// R18: grid 512 blocks (8 qtile-pairs x 64 heads) vs R17's 256 -- fixes the
// 1-block/CU occupancy starvation (4 waves/CU, all barrier-locked). LDS 40 KB
// (Ks 16 + Vt 16 + Ps 8) -> 4 blocks/CU capacity. Pair (p, 15-p): every block
// exactly 17 kv-units. Per-wave structure identical to v2 (32 q-rows as 2x16).
__global__ __launch_bounds__(128, 2) void flash_attn_kernel(
    const unsigned short* __restrict__ QKV, unsigned short* __restrict__ O) {
  __shared__ unsigned short Ks[64 * 128];    // 16 KB, swizzled row-major
  __shared__ unsigned short Vt[128 * 64];    // 16 KB, transposed + swizzled
  __shared__ unsigned short Ps[2][32 * 64];  // 8 KB, per-wave P, swizzled

  const int p  = blockIdx.x;   // pair 0..7
  const int bh = blockIdx.y;   // b*NH + h
  const int b  = bh >> 5;
  const int hh = bh & 31;
  const int t    = threadIdx.x;      // 0..127
  const int lane = t & 63;
  const int w    = t >> 6;           // 2 waves
  const int np   = lane & 15;
  const int hq   = lane >> 4;

  const size_t rowbase = (size_t)b * SEQ * LDQ;
  const unsigned short* Qg = QKV + rowbase + (size_t)hh * HD;
  const unsigned short* Kg = QKV + rowbase + 4096 + (size_t)hh * HD;
  const unsigned short* Vg = QKV + rowbase + 8192 + (size_t)hh * HD;
  unsigned short* Og = O + (size_t)b * SEQ * DIM + (size_t)hh * HD;

  // staging (128 threads): K: row t&63, col-half t>>6 (64 cols = 8 chunks)
  //                        V: rows (t&7)*8..+7, cols (t>>3)*8..+7
  const int krow = t & 63;
  const int kc0  = (t >> 6) * 64;
  const int vr0  = (t & 7) * 8;
  const int vc0  = (t >> 3) * 8;

  unsigned short* Pw = &Ps[w][0];
  const float SCALE = 0.08838834764831843f;  // 1/sqrt(128)

  bf16x8 vk[8], vv[8];

#pragma unroll 1
  for (int pass = 0; pass < 2; ++pass) {
    const int qt    = pass ? (15 - p) : p;
    const int nt    = qt + 1;
    const int qbase = qt * 64 + w * 32;

    bf16x8 qf[2][4];
#pragma unroll
    for (int rb = 0; rb < 2; ++rb)
#pragma unroll
      for (int kb = 0; kb < 4; ++kb)
        qf[rb][kb] = *(const bf16x8*)&Qg[(size_t)(qbase + rb * 16 + np) * LDQ + kb * 32 + hq * 8];

    f32x4 acc[2][8] = {};
    float m_run[2][4], l_run[2][4];
#pragma unroll
    for (int rb = 0; rb < 2; ++rb)
#pragma unroll
      for (int r = 0; r < 4; ++r) { m_run[rb][r] = -3.0e38f; l_run[rb][r] = 0.0f; }

    // prefetch tile 0 into regs
    {
      const unsigned short* kp = Kg + (size_t)krow * LDQ + kc0;
      const unsigned short* vp = Vg + (size_t)vr0 * LDQ + vc0;
#pragma unroll
      for (int jj = 0; jj < 8; ++jj) vk[jj] = *(const bf16x8*)(kp + jj * 8);
#pragma unroll
      for (int jj = 0; jj < 8; ++jj) vv[jj] = *(const bf16x8*)(vp + (size_t)jj * LDQ);
    }

#pragma unroll 1
    for (int kt = 0; kt < nt; ++kt) {
      __syncthreads();   // previous tile's LDS reads complete

      // ---- write staged regs to LDS (swizzled) ----
#pragma unroll
      for (int jj = 0; jj < 8; ++jj) {
        int c = (t >> 6) * 8 + jj;     // chunk index 0..15 within the 128-col row
        *(bf16x8*)((char*)Ks + krow * 256 + ((c ^ (krow & 7)) << 4)) = vk[jj];
      }
#pragma unroll
      for (int i = 0; i < 8; ++i) {
        int col = vc0 + i;
        bf16x8 sv;
#pragma unroll
        for (int jj = 0; jj < 8; ++jj) sv[jj] = vv[jj][i];
        *(bf16x8*)((char*)Vt + ((col * 128 + vr0 * 2) ^ ((col & 7) << 4))) = sv;
      }
      __syncthreads();   // LDS tile ready

      // ---- issue next tile's global loads (latency hides under compute) ----
      if (kt + 1 < nt) {
        const unsigned short* kp = Kg + (size_t)((kt + 1) * 64 + krow) * LDQ + kc0;
        const unsigned short* vp = Vg + (size_t)((kt + 1) * 64 + vr0) * LDQ + vc0;
#pragma unroll
        for (int jj = 0; jj < 8; ++jj) vk[jj] = *(const bf16x8*)(kp + jj * 8);
#pragma unroll
        for (int jj = 0; jj < 8; ++jj) vv[jj] = *(const bf16x8*)(vp + (size_t)jj * LDQ);
      }

      // ---- S = Q K^T ----
      f32x4 sc[4][2] = {};
#pragma unroll
      for (int ct = 0; ct < 4; ++ct) {
#pragma unroll
        for (int kb = 0; kb < 4; ++kb) {
          bf16x8 kf = *(const bf16x8*)((char*)Ks + (ct * 16 + np) * 256 +
                                       (((kb * 4 + hq) ^ (np & 7)) << 4));
          sc[ct][0] = __builtin_amdgcn_mfma_f32_16x16x32_bf16(qf[0][kb], kf, sc[ct][0], 0, 0, 0);
          sc[ct][1] = __builtin_amdgcn_mfma_f32_16x16x32_bf16(qf[1][kb], kf, sc[ct][1], 0, 0, 0);
        }
      }

      // ---- scale + causal mask (diagonal unit only: kt == qt) ----
      const bool maskt = (kt == qt);
#pragma unroll
      for (int ct = 0; ct < 4; ++ct) {
        int kvc = kt * 64 + ct * 16 + np;
#pragma unroll
        for (int rb = 0; rb < 2; ++rb)
#pragma unroll
          for (int r = 0; r < 4; ++r) {
            float v = sc[ct][rb][r] * SCALE;
            if (maskt && kvc > qbase + rb * 16 + hq * 4 + r) v = -1.0e9f;
            sc[ct][rb][r] = v;
          }
      }

      // ---- online softmax ----
      float sf[2][4];
#pragma unroll
      for (int rb = 0; rb < 2; ++rb)
#pragma unroll
        for (int r = 0; r < 4; ++r) {
          float tmax = fmaxf(fmaxf(sc[0][rb][r], sc[1][rb][r]),
                             fmaxf(sc[2][rb][r], sc[3][rb][r]));
          tmax = fmaxf(tmax, __shfl_xor(tmax, 1));
          tmax = fmaxf(tmax, __shfl_xor(tmax, 2));
          tmax = fmaxf(tmax, __shfl_xor(tmax, 4));
          tmax = fmaxf(tmax, __shfl_xor(tmax, 8));
          float mn = fmaxf(m_run[rb][r], tmax);
          sf[rb][r] = __expf(m_run[rb][r] - mn);
          m_run[rb][r] = mn;
        }

#pragma unroll
      for (int rb = 0; rb < 2; ++rb)
#pragma unroll
        for (int r = 0; r < 4; ++r) {
          int prow = rb * 16 + hq * 4 + r;
          int swz = (prow & 7) << 4;
          float rsum = 0.f;
#pragma unroll
          for (int ct = 0; ct < 4; ++ct) {
            float pv = __expf(sc[ct][rb][r] - m_run[rb][r]);
            rsum += pv;
            *(unsigned short*)((char*)Pw + ((prow * 128 + (ct * 16 + np) * 2) ^ swz)) = f2bfu(pv);
          }
          rsum += __shfl_xor(rsum, 1);
          rsum += __shfl_xor(rsum, 2);
          rsum += __shfl_xor(rsum, 4);
          rsum += __shfl_xor(rsum, 8);
          l_run[rb][r] = l_run[rb][r] * sf[rb][r] + rsum;
        }

      // ---- rescale O ----
#pragma unroll
      for (int rb = 0; rb < 2; ++rb)
#pragma unroll
        for (int nt2 = 0; nt2 < 8; ++nt2)
#pragma unroll
          for (int r = 0; r < 4; ++r)
            acc[rb][nt2][r] *= sf[rb][r];

      // ---- O += P V ----
#pragma unroll
      for (int kb2 = 0; kb2 < 2; ++kb2) {
        bf16x8 pa0 = *(const bf16x8*)((char*)Pw +
            (((0 * 16 + np) * 128 + kb2 * 64 + hq * 16) ^ ((np & 7) << 4)));
        bf16x8 pa1 = *(const bf16x8*)((char*)Pw +
            (((1 * 16 + np) * 128 + kb2 * 64 + hq * 16) ^ ((np & 7) << 4)));
#pragma unroll
        for (int nt2 = 0; nt2 < 8; ++nt2) {
          int col = nt2 * 16 + np;
          bf16x8 vf = *(const bf16x8*)((char*)Vt +
              ((col * 128 + kb2 * 64 + hq * 16) ^ ((col & 7) << 4)));
          acc[0][nt2] = __builtin_amdgcn_mfma_f32_16x16x32_bf16(pa0, vf, acc[0][nt2], 0, 0, 0);
          acc[1][nt2] = __builtin_amdgcn_mfma_f32_16x16x32_bf16(pa1, vf, acc[1][nt2], 0, 0, 0);
        }
      }
    }

    // ---- epilogue: O /= l ----
#pragma unroll
    for (int rb = 0; rb < 2; ++rb)
#pragma unroll
      for (int r = 0; r < 4; ++r) {
        float rl = 1.0f / l_run[rb][r];
        int orow = qbase + rb * 16 + hq * 4 + r;
#pragma unroll
        for (int nt2 = 0; nt2 < 8; ++nt2)
          Og[(size_t)orow * DIM + nt2 * 16 + np] = f2bfu(acc[rb][nt2][r] * rl);
      }
  }
}

extern "C" void kernel_launch(void* const* d_in, const int* in_sizes, int n_in,
                              void* d_out, int out_size, void* d_ws, size_t ws_size,
                              hipStream_t stream) {
  const float* x  = (const float*)d_in[0];
  const float* wq = (const float*)d_in[1];
  const float* bq = (const float*)d_in[2];
  const float* wk = (const float*)d_in[3];
  const float* bk = (const float*)d_in[4];
  const float* wv = (const float*)d_in[5];
  const float* bv = (const float*)d_in[6];
  const float* wo = (const float*)d_in[7];
  const float* bo = (const float*)d_in[8];
  float* out = (float*)d_out;

  char* ws = (char*)d_ws;
  unsigned short* wqkvb = (unsigned short*)(ws);                  // 96 MB [12288][4096]
  unsigned short* wob   = (unsigned short*)(ws + (96ll  << 20));  // 32 MB
  unsigned short* xb    = (unsigned short*)(ws + (128ll << 20));  // 16 MB
  unsigned short* qkv   = (unsigned short*)(ws + (144ll << 20));  // 48 MB [2048][12288]
  unsigned short* ab    = (unsigned short*)(ws + (192ll << 20));  // 16 MB
  float* biasqkv = (float*)(ws + (208ll << 20));                  // 48 KB
  float* cosT    = (float*)(ws + (208ll << 20) + (64  << 10));    // 256 KB
  float* sinT    = (float*)(ws + (208ll << 20) + (320 << 10));    // 256 KB

  // merged prep: bias concat + rope table + fp32->bf16 cvt (1 launch)
  prep_kernel<<<4096, 256, 0, stream>>>(x, wq, wk, wv, wo, bq, bk, bv,
                                        xb, wqkvb, wob, biasqkv, cosT, sinT);

  // fused QKV GEMM (+bias +RoPE in epilogue): [2048,4096]x[12288,4096]^T
  dim3 gq(LDQ / 128, MROWS / 128);  // (96, 16) = 1536 blocks
  gemm_m97p_kernel<unsigned short, true><<<gq, 256, 0, stream>>>(
      xb, wqkvb, biasqkv, qkv, MROWS, LDQ, DIM, cosT, sinT);

  dim3 ga(8, BATCH * NH);  // 8 qtile-pairs x 64 heads = 512 blocks
  flash_attn_kernel<<<ga, 128, 0, stream>>>(qkv, ab);

  // output GEMM: direct fp32 out + bias
  dim3 go(DIM / 128, MROWS / 128);  // (32, 16) = 512 blocks
  gemm_m97p_kernel<float, false><<<go, 256, 0, stream>>>(
      ab, wob, bo, out, MROWS, DIM, DIM, nullptr, nullptr);
}

// Round 19
// 514.554 us; speedup vs baseline: 1.3559x; 1.3559x over previous
//
#include <hip/hip_runtime.h>
#include <hip/hip_bf16.h>

#define DIM   4096
#define NH    32
#define HD    128
#define BATCH 2
#define SEQ   1024
#define MROWS (BATCH*SEQ)   // 2048
#define LDQ   12288         // fused qkv row stride

typedef __attribute__((ext_vector_type(8))) short bf16x8;
typedef __attribute__((ext_vector_type(4))) short s16x4;
typedef __attribute__((ext_vector_type(4))) float f32x4;

__device__ inline void gload_lds16(const void* g, void* l) {
  __builtin_amdgcn_global_load_lds(
      (const __attribute__((address_space(1))) void*)g,
      (__attribute__((address_space(3))) void*)l, 16, 0, 0);
}

__device__ inline float bf2f(short b) {
  unsigned u = ((unsigned)(unsigned short)b) << 16;
  return __uint_as_float(u);
}
__device__ inline unsigned short f2bfu(float f) {
  __hip_bfloat16 h = __float2bfloat16(f);
  return *reinterpret_cast<unsigned short*>(&h);
}

// ---------------- merged prep: bias concat + rope table + fp32->bf16 cvt -----
__global__ void prep_kernel(const float* __restrict__ x, const float* __restrict__ wq,
                            const float* __restrict__ wk, const float* __restrict__ wv,
                            const float* __restrict__ wo,
                            const float* __restrict__ bq, const float* __restrict__ bk,
                            const float* __restrict__ bv,
                            unsigned short* __restrict__ xb,
                            unsigned short* __restrict__ wqkvb,
                            unsigned short* __restrict__ wob,
                            float* __restrict__ biasqkv,
                            float* __restrict__ cosT, float* __restrict__ sinT) {
  const long NB = 12288;
  const long NR = 65536;            // SEQ * 64
  const long NX = 2l << 20;         // x float4 count
  const long NW = 4l << 20;         // per-weight float4 count
  const long total = NB + NR + NX + 4 * NW;
  long i = blockIdx.x * (long)blockDim.x + threadIdx.x;
  long stride = (long)gridDim.x * blockDim.x;
  for (; i < total; i += stride) {
    if (i < NB) {
      int j = (int)i;
      float v = (j < 4096) ? bq[j] : (j < 8192 ? bk[j - 4096] : bv[j - 8192]);
      biasqkv[j] = v;
    } else if (i < NB + NR) {
      int j = (int)(i - NB);
      int s = j >> 6, p = j & 63;
      float inv = powf(10000.0f, -((float)(2 * p)) / 128.0f);
      float a = (float)s * inv;
      cosT[j] = cosf(a);
      sinT[j] = sinf(a);
    } else {
      long j = i - NB - NR;
      const float* src; unsigned short* dst; long off;
      if (j < NX) { src = x; dst = xb; off = j; }
      else {
        long q = j - NX;
        int wsel = (int)(q >> 22);
        off = q & (NW - 1);
        if (wsel == 0)      { src = wq; dst = wqkvb; }
        else if (wsel == 1) { src = wk; dst = wqkvb + (size_t)DIM * DIM; }
        else if (wsel == 2) { src = wv; dst = wqkvb + 2 * (size_t)DIM * DIM; }
        else                { src = wo; dst = wob; }
      }
      float4 v = ((const float4*)src)[off];
      ushort4 o;
      o.x = f2bfu(v.x); o.y = f2bfu(v.y); o.z = f2bfu(v.z); o.w = f2bfu(v.w);
      ((ushort4*)dst)[off] = o;
    }
  }
}

// ---------------- m97+ GEMM: 128x128 tile, 3-slot rolling, depth 2 -----------
// R13/R15/R17-VERIFIED OPTIMUM: QKV ~280 us / 740 TF, FETCH 200 MB,
// conflicts 0, occupancy ~33% (3 blocks/CU). Do not change (all axes measured:
// schedule x6, occupancy x3, depth x2, XCD map x2, staging dtype x2).
template <typename OutT, bool ROPE>
__global__ __launch_bounds__(256, 2) void gemm_m97p_kernel(
    const unsigned short* __restrict__ A, const unsigned short* __restrict__ Bw,
    const float* __restrict__ bias, OutT* __restrict__ C,
    int M, int N, int Kstr,
    const float* __restrict__ cosT, const float* __restrict__ sinT) {
  __shared__ unsigned short As[3][128 * 32];   // 24 KB
  __shared__ unsigned short Bs[3][128 * 32];   // 24 KB
  const int t = threadIdx.x;
  const int lane = t & 63;
  const int w = t >> 6;                 // 4 waves
  const int wm = w >> 1, wn = w & 1;    // 2x2
  const int np = lane & 15, hq = lane >> 4;
  const int kc = ((hq ^ ((np >> 1) & 3)) << 3);

  // B-optimal XCD mapping: XCD = bid%8 owns bx in [k*sw, (k+1)*sw), by-major.
  int bid = blockIdx.y * gridDim.x + blockIdx.x;
  int k = bid & 7;
  int local = bid >> 3;
  int sw = gridDim.x >> 3;
  int bx = k * sw + local / gridDim.y;
  int by = local % gridDim.y;
  const int m0 = by * 128, n0 = bx * 128;
  const int H = Kstr >> 5;

  auto stage = [&](int slot, int kcol0) {
#pragma unroll
    for (int j = 0; j < 2; ++j) {
      int ci = j * 256 + t;                       // [0,512)
      int r = ci >> 2, p = ci & 3, g = p ^ ((r >> 1) & 3);
      gload_lds16(A + (size_t)(m0 + r) * Kstr + kcol0 + g * 8, &As[slot][ci * 8]);
    }
#pragma unroll
    for (int j = 0; j < 2; ++j) {
      int ci = j * 256 + t;
      int r = ci >> 2, p = ci & 3, g = p ^ ((r >> 1) & 3);
      gload_lds16(Bw + (size_t)(n0 + r) * Kstr + kcol0 + g * 8, &Bs[slot][ci * 8]);
    }
  };

  stage(0, 0); stage(1, 32);
  asm volatile("s_waitcnt vmcnt(4)" ::: "memory");
  __builtin_amdgcn_s_barrier();

  f32x4 acc[4][4] = {};

  int sl = 0;
#pragma unroll 1
  for (int u = 0; u < H; ++u) {
    const unsigned short* Asl = As[sl];
    const unsigned short* Bsl = Bs[sl];
    bf16x8 af[4], bfr[4];
#pragma unroll
    for (int i = 0; i < 4; ++i)
      af[i] = *(const bf16x8*)&Asl[(wm * 64 + i * 16 + np) * 32 + kc];
#pragma unroll
    for (int j = 0; j < 4; ++j)
      bfr[j] = *(const bf16x8*)&Bsl[(wn * 64 + j * 16 + np) * 32 + kc];

    if (u + 2 < H) {
      int ssl = sl + 2; if (ssl >= 3) ssl -= 3;
      stage(ssl, (u + 2) << 5);
    }

    __builtin_amdgcn_s_setprio(1);
#pragma unroll
    for (int i = 0; i < 4; ++i)
#pragma unroll
      for (int j = 0; j < 4; ++j)
        acc[i][j] = __builtin_amdgcn_mfma_f32_16x16x32_bf16(af[i], bfr[j], acc[i][j], 0, 0, 0);
    __builtin_amdgcn_s_setprio(0);

    if (u + 1 < H) {
      if (u + 2 < H) asm volatile("s_waitcnt vmcnt(4)" ::: "memory");
      else           asm volatile("s_waitcnt vmcnt(0)" ::: "memory");
      __builtin_amdgcn_s_barrier();
    }
    sl = (sl == 2) ? 0 : sl + 1;
  }

  const int orow0 = m0 + wm * 64;
  const int ocol0 = n0 + wn * 64 + np;
#pragma unroll
  for (int j = 0; j < 4; ++j) {
    const int col = ocol0 + j * 16;
    float bj = bias[col];
    const int p0 = (col & 127) >> 1;
    const bool even = (lane & 1) == 0;
    const bool do_rope = ROPE && (col < 8192);
#pragma unroll
    for (int i = 0; i < 4; ++i) {
#pragma unroll
      for (int r = 0; r < 4; ++r) {
        int orow = orow0 + i * 16 + hq * 4 + r;
        float v = acc[i][j][r] + bj;
        float pv = __shfl_xor(v, 1);
        if (do_rope) {
          int srow = orow & (SEQ - 1);
          float c = cosT[srow * 64 + p0];
          float s = sinT[srow * 64 + p0];
          v = even ? (v * c - pv * s) : (pv * s + v * c);
        }
        size_t off = (size_t)orow * N + col;
        if constexpr (sizeof(OutT) == 2)
          ((unsigned short*)C)[off] = f2bfu(v);
        else
          ((float*)C)[off] = v;
      }
    }
  }
}

// ---------------- Flash attention v2 (causal), QBLK=128, 256 thr = 4 waves ---
// R17-VERIFIED (~35 us). R18 falsified QBLK=64/128-thr variant (2x KV traffic
// + register blowup -> ~190 us). Do not change.
__global__ __launch_bounds__(256, 1) void flash_attn_kernel(
    const unsigned short* __restrict__ QKV, unsigned short* __restrict__ O) {
  __shared__ unsigned short Ks[64 * 128];    // swizzled row-major
  __shared__ unsigned short Vt[128 * 64];    // transposed + swizzled
  __shared__ unsigned short Ps[4][32 * 64];  // per-wave P, swizzled

  const int p  = blockIdx.x;   // pair 0..3
  const int bh = blockIdx.y;   // b*NH + h
  const int b  = bh >> 5;
  const int hh = bh & 31;
  const int t    = threadIdx.x;
  const int lane = t & 63;
  const int w    = t >> 6;
  const int np   = lane & 15;
  const int hq   = lane >> 4;

  const size_t rowbase = (size_t)b * SEQ * LDQ;
  const unsigned short* Qg = QKV + rowbase + (size_t)hh * HD;
  const unsigned short* Kg = QKV + rowbase + 4096 + (size_t)hh * HD;
  const unsigned short* Vg = QKV + rowbase + 8192 + (size_t)hh * HD;
  unsigned short* Og = O + (size_t)b * SEQ * DIM + (size_t)hh * HD;

  const int krow = t >> 2;
  const int kc0  = (t & 3) * 32;
  const int vr0  = (t & 15) * 4;
  const int vc0  = (t >> 4) * 8;

  unsigned short* Pw = &Ps[w][0];
  const float SCALE = 0.08838834764831843f;  // 1/sqrt(128)

  bf16x8 vk[4], vv[4];

#pragma unroll 1
  for (int pass = 0; pass < 2; ++pass) {
    const int qt    = pass ? (7 - p) : p;
    const int nt    = 2 * qt + 2;
    const int qbase = qt * 128 + w * 32;

    bf16x8 qf[2][4];
#pragma unroll
    for (int rb = 0; rb < 2; ++rb)
#pragma unroll
      for (int kb = 0; kb < 4; ++kb)
        qf[rb][kb] = *(const bf16x8*)&Qg[(size_t)(qbase + rb * 16 + np) * LDQ + kb * 32 + hq * 8];

    f32x4 acc[2][8] = {};
    float m_run[2][4], l_run[2][4];
#pragma unroll
    for (int rb = 0; rb < 2; ++rb)
#pragma unroll
      for (int r = 0; r < 4; ++r) { m_run[rb][r] = -3.0e38f; l_run[rb][r] = 0.0f; }

    {
      const unsigned short* kp = Kg + (size_t)krow * LDQ + kc0;
      const unsigned short* vp = Vg + (size_t)vr0 * LDQ + vc0;
#pragma unroll
      for (int jj = 0; jj < 4; ++jj) vk[jj] = *(const bf16x8*)(kp + jj * 8);
#pragma unroll
      for (int jj = 0; jj < 4; ++jj) vv[jj] = *(const bf16x8*)(vp + (size_t)jj * LDQ);
    }

#pragma unroll 1
    for (int kt = 0; kt < nt; ++kt) {
      __syncthreads();

#pragma unroll
      for (int jj = 0; jj < 4; ++jj) {
        int c = (t & 3) * 4 + jj;
        *(bf16x8*)((char*)Ks + krow * 256 + ((c ^ (krow & 7)) << 4)) = vk[jj];
      }
#pragma unroll
      for (int i = 0; i < 8; ++i) {
        int col = vc0 + i;
        s16x4 sv;
        sv[0] = vv[0][i]; sv[1] = vv[1][i]; sv[2] = vv[2][i]; sv[3] = vv[3][i];
        *(s16x4*)((char*)Vt + ((col * 128 + vr0 * 2) ^ ((col & 7) << 4))) = sv;
      }
      __syncthreads();

      if (kt + 1 < nt) {
        const unsigned short* kp = Kg + (size_t)((kt + 1) * 64 + krow) * LDQ + kc0;
        const unsigned short* vp = Vg + (size_t)((kt + 1) * 64 + vr0) * LDQ + vc0;
#pragma unroll
        for (int jj = 0; jj < 4; ++jj) vk[jj] = *(const bf16x8*)(kp + jj * 8);
#pragma unroll
        for (int jj = 0; jj < 4; ++jj) vv[jj] = *(const bf16x8*)(vp + (size_t)jj * LDQ);
      }

      f32x4 sc[4][2] = {};
#pragma unroll
      for (int ct = 0; ct < 4; ++ct) {
#pragma unroll
        for (int kb = 0; kb < 4; ++kb) {
          bf16x8 kf = *(const bf16x8*)((char*)Ks + (ct * 16 + np) * 256 +
                                       (((kb * 4 + hq) ^ (np & 7)) << 4));
          sc[ct][0] = __builtin_amdgcn_mfma_f32_16x16x32_bf16(qf[0][kb], kf, sc[ct][0], 0, 0, 0);
          sc[ct][1] = __builtin_amdgcn_mfma_f32_16x16x32_bf16(qf[1][kb], kf, sc[ct][1], 0, 0, 0);
        }
      }

      const bool maskt = (kt >= 2 * qt);
#pragma unroll
      for (int ct = 0; ct < 4; ++ct) {
        int kvc = kt * 64 + ct * 16 + np;
#pragma unroll
        for (int rb = 0; rb < 2; ++rb)
#pragma unroll
          for (int r = 0; r < 4; ++r) {
            float v = sc[ct][rb][r] * SCALE;
            if (maskt && kvc > qbase + rb * 16 + hq * 4 + r) v = -1.0e9f;
            sc[ct][rb][r] = v;
          }
      }

      float sf[2][4];
#pragma unroll
      for (int rb = 0; rb < 2; ++rb)
#pragma unroll
        for (int r = 0; r < 4; ++r) {
          float tmax = fmaxf(fmaxf(sc[0][rb][r], sc[1][rb][r]),
                             fmaxf(sc[2][rb][r], sc[3][rb][r]));
          tmax = fmaxf(tmax, __shfl_xor(tmax, 1));
          tmax = fmaxf(tmax, __shfl_xor(tmax, 2));
          tmax = fmaxf(tmax, __shfl_xor(tmax, 4));
          tmax = fmaxf(tmax, __shfl_xor(tmax, 8));
          float mn = fmaxf(m_run[rb][r], tmax);
          sf[rb][r] = __expf(m_run[rb][r] - mn);
          m_run[rb][r] = mn;
        }

#pragma unroll
      for (int rb = 0; rb < 2; ++rb)
#pragma unroll
        for (int r = 0; r < 4; ++r) {
          int prow = rb * 16 + hq * 4 + r;
          int swz = (prow & 7) << 4;
          float rsum = 0.f;
#pragma unroll
          for (int ct = 0; ct < 4; ++ct) {
            float pv = __expf(sc[ct][rb][r] - m_run[rb][r]);
            rsum += pv;
            *(unsigned short*)((char*)Pw + ((prow * 128 + (ct * 16 + np) * 2) ^ swz)) = f2bfu(pv);
          }
          rsum += __shfl_xor(rsum, 1);
          rsum += __shfl_xor(rsum, 2);
          rsum += __shfl_xor(rsum, 4);
          rsum += __shfl_xor(rsum, 8);
          l_run[rb][r] = l_run[rb][r] * sf[rb][r] + rsum;
        }

#pragma unroll
      for (int rb = 0; rb < 2; ++rb)
#pragma unroll
        for (int nt2 = 0; nt2 < 8; ++nt2)
#pragma unroll
          for (int r = 0; r < 4; ++r)
            acc[rb][nt2][r] *= sf[rb][r];

#pragma unroll
      for (int kb2 = 0; kb2 < 2; ++kb2) {
        bf16x8 pa0 = *(const bf16x8*)((char*)Pw +
            (((0 * 16 + np) * 128 + kb2 * 64 + hq * 16) ^ ((np & 7) << 4)));
        bf16x8 pa1 = *(const bf16x8*)((char*)Pw +
            (((1 * 16 + np) * 128 + kb2 * 64 + hq * 16) ^ ((np & 7) << 4)));
#pragma unroll
        for (int nt2 = 0; nt2 < 8; ++nt2) {
          int col = nt2 * 16 + np;
          bf16x8 vf = *(const bf16x8*)((char*)Vt +
              ((col * 128 + kb2 * 64 + hq * 16) ^ ((col & 7) << 4)));
          acc[0][nt2] = __builtin_amdgcn_mfma_f32_16x16x32_bf16(pa0, vf, acc[0][nt2], 0, 0, 0);
          acc[1][nt2] = __builtin_amdgcn_mfma_f32_16x16x32_bf16(pa1, vf, acc[1][nt2], 0, 0, 0);
        }
      }
    }

#pragma unroll
    for (int rb = 0; rb < 2; ++rb)
#pragma unroll
      for (int r = 0; r < 4; ++r) {
        float rl = 1.0f / l_run[rb][r];
        int orow = qbase + rb * 16 + hq * 4 + r;
#pragma unroll
        for (int nt2 = 0; nt2 < 8; ++nt2)
          Og[(size_t)orow * DIM + nt2 * 16 + np] = f2bfu(acc[rb][nt2][r] * rl);
      }
  }
}

extern "C" void kernel_launch(void* const* d_in, const int* in_sizes, int n_in,
                              void* d_out, int out_size, void* d_ws, size_t ws_size,
                              hipStream_t stream) {
  const float* x  = (const float*)d_in[0];
  const float* wq = (const float*)d_in[1];
  const float* bq = (const float*)d_in[2];
  const float* wk = (const float*)d_in[3];
  const float* bk = (const float*)d_in[4];
  const float* wv = (const float*)d_in[5];
  const float* bv = (const float*)d_in[6];
  const float* wo = (const float*)d_in[7];
  const float* bo = (const float*)d_in[8];
  float* out = (float*)d_out;

  char* ws = (char*)d_ws;
  unsigned short* wqkvb = (unsigned short*)(ws);                  // 96 MB [12288][4096]
  unsigned short* wob   = (unsigned short*)(ws + (96ll  << 20));  // 32 MB
  unsigned short* xb    = (unsigned short*)(ws + (128ll << 20));  // 16 MB
  unsigned short* qkv   = (unsigned short*)(ws + (144ll << 20));  // 48 MB [2048][12288]
  unsigned short* ab    = (unsigned short*)(ws + (192ll << 20));  // 16 MB
  float* biasqkv = (float*)(ws + (208ll << 20));                  // 48 KB
  float* cosT    = (float*)(ws + (208ll << 20) + (64  << 10));    // 256 KB
  float* sinT    = (float*)(ws + (208ll << 20) + (320 << 10));    // 256 KB

  // merged prep: bias concat + rope table + fp32->bf16 cvt (1 launch)
  prep_kernel<<<4096, 256, 0, stream>>>(x, wq, wk, wv, wo, bq, bk, bv,
                                        xb, wqkvb, wob, biasqkv, cosT, sinT);

  // fused QKV GEMM (+bias +RoPE in epilogue): [2048,4096]x[12288,4096]^T
  dim3 gq(LDQ / 128, MROWS / 128);  // (96, 16) = 1536 blocks
  gemm_m97p_kernel<unsigned short, true><<<gq, 256, 0, stream>>>(
      xb, wqkvb, biasqkv, qkv, MROWS, LDQ, DIM, cosT, sinT);

  dim3 ga(4, BATCH * NH);  // 4 qtile-pairs x 64 heads = 256 blocks
  flash_attn_kernel<<<ga, 256, 0, stream>>>(qkv, ab);

  // output GEMM: direct fp32 out + bias
  dim3 go(DIM / 128, MROWS / 128);  // (32, 16) = 512 blocks
  gemm_m97p_kernel<float, false><<<go, 256, 0, stream>>>(
      ab, wob, bo, out, MROWS, DIM, DIM, nullptr, nullptr);
}